// Round 19
// baseline (282.060 us; speedup 1.0000x reference)
//
#include <hip/hip_runtime.h>
#include <hip/hip_bf16.h>
#include <stdint.h>

#define Bb 2
#define Ss 4096
#define Dd 1024
#define Hh 16
#define DKk 64

typedef __attribute__((ext_vector_type(8))) short bf16x8;
typedef __attribute__((ext_vector_type(4))) float f32x4;
typedef __attribute__((ext_vector_type(16))) float f32x16;

#define MFMA16(a, b, c) __builtin_amdgcn_mfma_f32_32x32x16_bf16(a, b, c, 0, 0, 0)

__device__ __forceinline__ unsigned short f2bf(float f) {
    union { float f; unsigned int u; } x; x.f = f;
    return (unsigned short)((x.u + 0x7fffu + ((x.u >> 16) & 1u)) >> 16);
}

__device__ __forceinline__ void gload16(const void* g, void* l) {
    __builtin_amdgcn_global_load_lds(
        (const __attribute__((address_space(1))) void*)g,
        (__attribute__((address_space(3))) void*)l, 16, 0, 0);
}

// ---------------- fp32 -> bf16 convert, weights only (4 x 1M elements) ------
__global__ __launch_bounds__(256) void cvt_w(const float* __restrict__ wq, const float* __restrict__ wk,
                                             const float* __restrict__ wv, const float* __restrict__ w0,
                                             unsigned short* __restrict__ dst) {
    const int i = blockIdx.x * 256 + threadIdx.x;    // 0 .. 4*262144-1 (float4 units)
    const int r = i >> 18, j = i & 262143;
    const float* s = r == 0 ? wq : (r == 1 ? wk : (r == 2 ? wv : w0));
    const float4 v = ((const float4*)s)[j];
    ushort4 o;
    o.x = f2bf(v.x); o.y = f2bf(v.y); o.z = f2bf(v.z); o.w = f2bf(v.w);
    ((ushort4*)dst)[i] = o;
}

// ---------------- GEMM: Y[M,N] = A[M,K] * W[N,K]^T ---------------------------
// AF32=1: A is fp32, reg-staged (dwordx4 prefetch -> cvt_pk -> ds_write),
// prefetch of tile kt+1 issued during the MFMA region (T14 async split).
// AF32=0: A is bf16 via global_load_lds (original m97 path).
// MODE 0: bf16 out. MODE 1: bf16 scattered to vt[B,H,DK,S]. MODE 2: f32 out.
// MODE 3: bf16 out scaled by 0.125*log2(e)  (softmax scale folded into Q).
template <int MODE, int AF32>
__global__ __launch_bounds__(256) void gemm_bt(const void* __restrict__ Av,
                                               const unsigned short* __restrict__ W,
                                               void* __restrict__ Y) {
    __shared__ unsigned short As[128 * 32];
    __shared__ unsigned short Bs[128 * 32];
    const int t = threadIdx.x;
    const int wid = t >> 6, lane = t & 63, q4 = lane >> 4, l16 = lane & 15;
    const int wr = wid >> 1, wc = wid & 1;
    const int arow0 = blockIdx.x * 128;
    const int wrow0 = blockIdx.y * 128;
    const int o0 = t * 16, o1 = 4096 + t * 16;       // staging byte offsets
    // bf16-A staging geometry
    const unsigned short* Ab = (const unsigned short*)Av;
    const int r0 = o0 >> 6, c0 = (o0 & 63) >> 1;
    const int r1 = o1 >> 6, c1 = (o1 & 63) >> 1;
    // f32-A staging geometry: thread covers row ar, 16 floats at col ac
    const float* Af = (const float*)Av;
    const int ar = t >> 1, ac = (t & 1) * 16;
    const float* aptr = Af + (long)(arow0 + ar) * 1024 + ac;
    const int adst = ar * 64 + (t & 1) * 32;         // byte offset in As

    float4 pf0, pf1, pf2, pf3;                       // A prefetch regs (16 f32)
    if (AF32) {
        const float4* p = (const float4*)aptr;
        pf0 = p[0]; pf1 = p[1]; pf2 = p[2]; pf3 = p[3];
    }

    f32x4 acc[4][4] = {};
    for (int kt = 0; kt < 32; kt++) {
        __syncthreads();
        if (AF32) {
            unsigned w[8];
            asm("v_cvt_pk_bf16_f32 %0, %1, %2" : "=v"(w[0]) : "v"(pf0.x), "v"(pf0.y));
            asm("v_cvt_pk_bf16_f32 %0, %1, %2" : "=v"(w[1]) : "v"(pf0.z), "v"(pf0.w));
            asm("v_cvt_pk_bf16_f32 %0, %1, %2" : "=v"(w[2]) : "v"(pf1.x), "v"(pf1.y));
            asm("v_cvt_pk_bf16_f32 %0, %1, %2" : "=v"(w[3]) : "v"(pf1.z), "v"(pf1.w));
            asm("v_cvt_pk_bf16_f32 %0, %1, %2" : "=v"(w[4]) : "v"(pf2.x), "v"(pf2.y));
            asm("v_cvt_pk_bf16_f32 %0, %1, %2" : "=v"(w[5]) : "v"(pf2.z), "v"(pf2.w));
            asm("v_cvt_pk_bf16_f32 %0, %1, %2" : "=v"(w[6]) : "v"(pf3.x), "v"(pf3.y));
            asm("v_cvt_pk_bf16_f32 %0, %1, %2" : "=v"(w[7]) : "v"(pf3.z), "v"(pf3.w));
            uint4 d0 = make_uint4(w[0], w[1], w[2], w[3]);
            uint4 d1 = make_uint4(w[4], w[5], w[6], w[7]);
            *(uint4*)((char*)As + adst) = d0;
            *(uint4*)((char*)As + adst + 16) = d1;
        } else {
            gload16(Ab + (long)(arow0 + r0) * 1024 + kt * 32 + c0, (char*)As + o0);
            gload16(Ab + (long)(arow0 + r1) * 1024 + kt * 32 + c1, (char*)As + o1);
        }
        gload16(W + (long)(wrow0 + r0) * 1024 + kt * 32 + c0, (char*)Bs + o0);
        gload16(W + (long)(wrow0 + r1) * 1024 + kt * 32 + c1, (char*)Bs + o1);
        __syncthreads();
        if (AF32 && kt < 31) {                       // prefetch next A tile
            const float4* p = (const float4*)(aptr + (kt + 1) * 32);
            pf0 = p[0]; pf1 = p[1]; pf2 = p[2]; pf3 = p[3];
        }
        bf16x8 a[4], b[4];
#pragma unroll
        for (int m = 0; m < 4; m++)
            a[m] = *(const bf16x8*)((const char*)As + (wr * 64 + m * 16 + l16) * 64 + q4 * 16);
#pragma unroll
        for (int n = 0; n < 4; n++)
            b[n] = *(const bf16x8*)((const char*)Bs + (wc * 64 + n * 16 + l16) * 64 + q4 * 16);
#pragma unroll
        for (int m = 0; m < 4; m++)
#pragma unroll
            for (int n = 0; n < 4; n++)
                acc[m][n] = __builtin_amdgcn_mfma_f32_16x16x32_bf16(a[m], b[n], acc[m][n], 0, 0, 0);
    }

    const int rb = arow0 + wr * 64, cb = wrow0 + wc * 64;
#pragma unroll
    for (int m = 0; m < 4; m++)
#pragma unroll
        for (int n = 0; n < 4; n++)
#pragma unroll
            for (int r = 0; r < 4; r++) {
                const int row = rb + m * 16 + q4 * 4 + r;
                const int col = cb + n * 16 + l16;
                const float v = acc[m][n][r];
                if (MODE == 0) {
                    ((unsigned short*)Y)[(long)row * 1024 + col] = f2bf(v);
                } else if (MODE == 1) {
                    const int bb = row >> 12, s = row & 4095;
                    const int hh = col >> 6, dk = col & 63;
                    ((unsigned short*)Y)[(((long)(bb * Hh + hh) * DKk + dk) << 12) + s] = f2bf(v);
                } else if (MODE == 3) {
                    ((unsigned short*)Y)[(long)row * 1024 + col] = f2bf(v * 0.1803368801111244f);
                } else {
                    ((float*)Y)[(long)row * 1024 + col] = v;
                }
            }
}

// ---------------- flash attention: QB=256, 8 waves x 32 q-rows (R17) --------
// grid (S/256, H, B), 512 threads = 8 waves; each wave owns 32 q-rows.
// Maxless exp2 softmax (Q pre-scaled by 0.125*log2e); li via pairwise adds +
// shfl_xor(32). PV: O^T = V^T P^T, P in-register (cvt_pk + permlane32_swap).
// R12 sync skeleton: [compute][barrier][stage kt+2 + vmcnt(2)][barrier].
// LDS (32KB): [0,8K) K0 | [8K,16K) V0 | [16K,24K) K1 | [24K,32K) V1;
// Q staging (32KB) strictly precedes K/V staging (vmcnt(0) fence).
__global__ __launch_bounds__(512, 4) void attn_fwd(const unsigned short* __restrict__ qp,
                                                   const unsigned short* __restrict__ kp,
                                                   const unsigned short* __restrict__ vt,
                                                   unsigned short* __restrict__ xo) {
    __shared__ __align__(16) char smem[32768];
    const int t = threadIdx.x;
    const int wid = t >> 6, lane = t & 63;
    const int l5 = lane & 31;
    const int ihi = lane >> 5;
    const int swz5 = (l5 & 7) ^ ((l5 >> 3) & 3);
    const int qt = blockIdx.x, h = blockIdx.y, b = blockIdx.z;
    const unsigned short* qbase = qp + ((long)b * Ss + qt * 256) * Dd + h * 64;
    const unsigned short* kbase = kp + (long)b * Ss * Dd + h * 64;
    const unsigned short* vbase = vt + (long)(b * Hh + h) * DKk * Ss;

    // staging geometry: 512 threads cover 8KB/call; row r0 in 0..63
    const int r0 = t >> 3;
    const int s0i = t & 7;
    const int cb0 = s0i ^ (r0 & 7) ^ ((r0 >> 3) & 3);  // logical col-block
    const int o0 = t * 16;                             // 0..8191
    const unsigned short* qsrc = qbase + (long)r0 * Dd + cb0 * 8;
    const unsigned short* ksrc = kbase + (long)r0 * Dd + cb0 * 8;
    const unsigned short* vsrc = vbase + (long)r0 * Ss + cb0 * 8;

    // ---- phase 1: Q (32KB, 4 calls) fully lands before K/V staging
#pragma unroll
    for (int i = 0; i < 4; i++)
        gload16(qsrc + (long)i * 64 * Dd, smem + i * 8192 + o0);
    asm volatile("s_waitcnt vmcnt(0)" ::: "memory");
    __builtin_amdgcn_s_barrier();
    asm volatile("" ::: "memory");

    // Q fragments: wave wid owns q-rows wid*32..wid*32+31 (chunk wid, 4KB)
    bf16x8 bQ[4];
#pragma unroll
    for (int m = 0; m < 4; m++) {
        const int slot = (m * 2 + ihi) ^ swz5;
        bQ[m] = *(const bf16x8*)(smem + wid * 4096 + l5 * 128 + (slot << 4));
    }
    asm volatile("s_waitcnt lgkmcnt(0)" ::: "memory");
    __builtin_amdgcn_s_barrier();                      // all waves done with Q
    asm volatile("" ::: "memory");

    // ---- phase 2: stage tiles 0 and 1 (K: 1 call, V: 1 call each)
    gload16(ksrc,                smem + o0);
    gload16(vsrc,                smem + 8192 + o0);
    gload16(ksrc + 64 * Dd,      smem + 16384 + o0);
    gload16(vsrc + 64,           smem + 24576 + o0);
    const unsigned short* pk = ksrc + 128 * Dd;
    const unsigned short* pv = vsrc + 128;
    asm volatile("s_waitcnt vmcnt(2)" ::: "memory");   // tile 0 landed
    __builtin_amdgcn_s_barrier();
    asm volatile("" ::: "memory");

    int adm[4];
#pragma unroll
    for (int m = 0; m < 4; m++)
        adm[m] = l5 * 128 + ((((m * 2 + ihi) ^ swz5)) << 4);

    f32x16 accO[2] = {};                     // [dblk]
    float li = 0.f;

    for (int kt2 = 0; kt2 < 64; kt2 += 2) {
#pragma unroll
        for (int hf = 0; hf < 2; hf++) {
            const int kt = kt2 + hf;
            const int BO = hf << 14;
            const char* Kc = smem + BO;
            const char* Vc = smem + BO + 8192;
            // ---- S^T = K Q^T : D[row=k][col=q=l5]
            f32x16 accS[2] = {};             // [kb]
            __builtin_amdgcn_s_setprio(1);
#pragma unroll
            for (int m = 0; m < 4; m++) {
                const bf16x8 aK0 = *(const bf16x8*)(Kc + adm[m]);
                const bf16x8 aK1 = *(const bf16x8*)(Kc + 4096 + adm[m]);
                accS[0] = MFMA16(aK0, bQ[m], accS[0]);
                accS[1] = MFMA16(aK1, bQ[m], accS[1]);
            }
            // ---- PV: per m-group, exp2/cvt/permlane then 2 MFMA
            float ps = 0.f;
#pragma unroll
            for (int m = 0; m < 4; m++) {
                const bf16x8 aV0 = *(const bf16x8*)(Vc + adm[m]);
                const bf16x8 aV1 = *(const bf16x8*)(Vc + 4096 + adm[m]);
                const int kb = m >> 1, sx = (m & 1) * 2;
                unsigned w00, w01, w10, w11;
                {
                    const float a0 = __builtin_amdgcn_exp2f(accS[kb][4 * sx + 0]);
                    const float a1 = __builtin_amdgcn_exp2f(accS[kb][4 * sx + 1]);
                    const float a2 = __builtin_amdgcn_exp2f(accS[kb][4 * sx + 2]);
                    const float a3 = __builtin_amdgcn_exp2f(accS[kb][4 * sx + 3]);
                    const float b0 = __builtin_amdgcn_exp2f(accS[kb][4 * sx + 4]);
                    const float b1 = __builtin_amdgcn_exp2f(accS[kb][4 * sx + 5]);
                    const float b2 = __builtin_amdgcn_exp2f(accS[kb][4 * sx + 6]);
                    const float b3 = __builtin_amdgcn_exp2f(accS[kb][4 * sx + 7]);
                    ps += ((a0 + a1) + (a2 + a3)) + ((b0 + b1) + (b2 + b3));
                    asm("v_cvt_pk_bf16_f32 %0, %1, %2" : "=v"(w00) : "v"(a0), "v"(a1));
                    asm("v_cvt_pk_bf16_f32 %0, %1, %2" : "=v"(w01) : "v"(a2), "v"(a3));
                    asm("v_cvt_pk_bf16_f32 %0, %1, %2" : "=v"(w10) : "v"(b0), "v"(b1));
                    asm("v_cvt_pk_bf16_f32 %0, %1, %2" : "=v"(w11) : "v"(b2), "v"(b3));
                }
                asm("v_permlane32_swap_b32 %0, %1" : "+v"(w00), "+v"(w10));
                asm("v_permlane32_swap_b32 %0, %1" : "+v"(w01), "+v"(w11));
                union { unsigned u[4]; bf16x8 v; } fr;
                fr.u[0] = w00; fr.u[1] = w01; fr.u[2] = w10; fr.u[3] = w11;
                accO[0] = MFMA16(aV0, fr.v, accO[0]);
                accO[1] = MFMA16(aV1, fr.v, accO[1]);
            }
            __builtin_amdgcn_s_setprio(0);
            li += ps + __shfl_xor(ps, 32, 64);
            // ---- counted-vmcnt barrier pair (R12 skeleton)
            __builtin_amdgcn_s_barrier();          // all waves done reading buf[hf]
            asm volatile("" ::: "memory");
            if (kt < 62) {
                char* dst = smem + BO;
                gload16(pk, dst + o0);
                gload16(pv, dst + 8192 + o0);
                pk += 64 * Dd;
                pv += 64;
                asm volatile("s_waitcnt vmcnt(2)" ::: "memory");  // tile kt+1 landed
            } else {
                asm volatile("s_waitcnt vmcnt(0)" ::: "memory");  // tail: drain
            }
            __builtin_amdgcn_s_barrier();          // buf[hf^1] readable by all
            asm volatile("" ::: "memory");
        }
    }

    // ---- epilogue: O^T -> LDS transpose (whole 32KB) -> coalesced store
    const float rli = 1.0f / li;
#pragma unroll
    for (int dblk = 0; dblk < 2; dblk++)
#pragma unroll
        for (int tt = 0; tt < 8; tt++) {
            const unsigned short b0 = f2bf(accO[dblk][2 * tt] * rli);
            const unsigned short b1 = f2bf(accO[dblk][2 * tt + 1] * rli);
            const int slot = (dblk * 4 + (tt >> 1)) ^ swz5;
            const int phys = wid * 4096 + l5 * 128 + (slot << 4) + ihi * 8 + (tt & 1) * 4;
            *(unsigned*)(smem + phys) = ((unsigned)b1 << 16) | b0;
        }
    __syncthreads();
#pragma unroll
    for (int p = 0; p < 4; p++) {
        const uint4 val = *(const uint4*)(smem + p * 8192 + o0);
        const long row = (long)qt * 256 + p * 64 + r0;
        *(uint4*)(xo + ((long)b * Ss + row) * Dd + h * 64 + cb0 * 8) = val;
    }
}

extern "C" void kernel_launch(void* const* d_in, const int* in_sizes, int n_in,
                              void* d_out, int out_size, void* d_ws, size_t ws_size,
                              hipStream_t stream) {
    const float* q  = (const float*)d_in[0];
    const float* k  = (const float*)d_in[1];
    const float* v  = (const float*)d_in[2];
    const float* wq = (const float*)d_in[3];
    const float* wk = (const float*)d_in[4];
    const float* wv = (const float*)d_in[5];
    const float* w0 = (const float*)d_in[6];

    unsigned short* ws = (unsigned short*)d_ws;
    const long NE = (long)Bb * Ss * Dd;        // 8388608
    unsigned short* kp  = ws;                  // kp [B,S,D] bf16
    unsigned short* vt  = ws + NE;             // vt [B,H,DK,S] bf16
    unsigned short* xo  = ws + 2 * NE;         // attn output bf16
    unsigned short* x1  = ws + 3 * NE;         // qp (pre-scaled by 0.125*log2e)
    unsigned short* wqb = ws + 4 * NE;
    unsigned short* wkb = wqb + 1048576;
    unsigned short* wvb = wkb + 1048576;
    unsigned short* w0b = wvb + 1048576;

    cvt_w<<<4096, 256, 0, stream>>>(wq, wk, wv, w0, wqb);

    dim3 gg(64, 8);
    gemm_bt<3, 1><<<gg, 256, 0, stream>>>(q, wqb, x1);   // qp * 0.125*log2e
    gemm_bt<0, 1><<<gg, 256, 0, stream>>>(k, wkb, kp);   // kp
    gemm_bt<1, 1><<<gg, 256, 0, stream>>>(v, wvb, vt);   // vt
    dim3 ga(16, 16, 2);
    attn_fwd<<<ga, 512, 0, stream>>>(x1, kp, vt, xo);
    gemm_bt<2, 0><<<gg, 256, 0, stream>>>(xo, w0b, (float*)d_out);
}

// Round 20
// 267.913 us; speedup vs baseline: 1.0528x; 1.0528x over previous
//
#include <hip/hip_runtime.h>
#include <hip/hip_bf16.h>
#include <stdint.h>

#define Bb 2
#define Ss 4096
#define Dd 1024
#define Hh 16
#define DKk 64

typedef __attribute__((ext_vector_type(8))) short bf16x8;
typedef __attribute__((ext_vector_type(4))) float f32x4;
typedef __attribute__((ext_vector_type(16))) float f32x16;

#define MFMA16(a, b, c) __builtin_amdgcn_mfma_f32_32x32x16_bf16(a, b, c, 0, 0, 0)

__device__ __forceinline__ unsigned short f2bf(float f) {
    union { float f; unsigned int u; } x; x.f = f;
    return (unsigned short)((x.u + 0x7fffu + ((x.u >> 16) & 1u)) >> 16);
}

__device__ __forceinline__ void gload16(const void* g, void* l) {
    __builtin_amdgcn_global_load_lds(
        (const __attribute__((address_space(1))) void*)g,
        (__attribute__((address_space(3))) void*)l, 16, 0, 0);
}

// ---------------- fp32 -> bf16 convert, all 7 tensors in one launch ---------
__global__ __launch_bounds__(256) void cvt_all(const float* __restrict__ q, const float* __restrict__ k,
                                               const float* __restrict__ v, const float* __restrict__ wq,
                                               const float* __restrict__ wk, const float* __restrict__ wv,
                                               const float* __restrict__ w0, unsigned short* __restrict__ ws) {
    const int QKV4 = 3 * 2097152;          // q,k,v: NE/4 each
    const int TOT4 = QKV4 + 4 * 262144;    // + 4 weights
    int i = blockIdx.x * 256 + threadIdx.x;
    const int stride = gridDim.x * 256;
    ushort4* out = (ushort4*)ws;
    for (; i < TOT4; i += stride) {
        const float4* src;
        int di;
        if (i < QKV4) {
            const int r = i >> 21;
            const float* s = r == 0 ? q : (r == 1 ? k : v);
            src = (const float4*)s + (i & 2097151);
            di = i;
        } else {
            const int j = i - QKV4;
            const int r = j >> 18;
            const float* s = r == 0 ? wq : (r == 1 ? wk : (r == 2 ? wv : w0));
            src = (const float4*)s + (j & 262143);
            di = i + 2097152;              // weights live after the x1 slot
        }
        const float4 vv = *src;
        ushort4 o;
        o.x = f2bf(vv.x); o.y = f2bf(vv.y); o.z = f2bf(vv.z); o.w = f2bf(vv.w);
        out[di] = o;
    }
}

// ---------------- GEMM: Y[M,N] = A[M,K] * W[N,K]^T  (m97 structure) ----------
// MODE 0: bf16 out. MODE 1: bf16 scattered to vt[B,H,DK,S]. MODE 2: f32 out.
// MODE 3: bf16 out scaled by 0.125*log2(e)  (softmax scale folded into Q).
template <int MODE>
__global__ __launch_bounds__(256) void gemm_bt(const unsigned short* __restrict__ A,
                                               const unsigned short* __restrict__ W,
                                               void* __restrict__ Y) {
    __shared__ unsigned short As[128 * 32];
    __shared__ unsigned short Bs[128 * 32];
    const int t = threadIdx.x;
    const int wid = t >> 6, lane = t & 63, q4 = lane >> 4, l16 = lane & 15;
    const int wr = wid >> 1, wc = wid & 1;
    const int arow0 = blockIdx.x * 128;
    const int wrow0 = blockIdx.y * 128;
    f32x4 acc[4][4] = {};
    for (int kt = 0; kt < 1024; kt += 32) {
        __syncthreads();
#pragma unroll
        for (int i = 0; i < 2; i++) {
            const int o = i * 4096 + t * 16;
            const int r = o >> 6, c = (o & 63) >> 1;
            gload16(A + (long)(arow0 + r) * 1024 + kt + c, (char*)As + o);
            gload16(W + (long)(wrow0 + r) * 1024 + kt + c, (char*)Bs + o);
        }
        __syncthreads();
        bf16x8 a[4], b[4];
#pragma unroll
        for (int m = 0; m < 4; m++)
            a[m] = *(const bf16x8*)((const char*)As + (wr * 64 + m * 16 + l16) * 64 + q4 * 16);
#pragma unroll
        for (int n = 0; n < 4; n++)
            b[n] = *(const bf16x8*)((const char*)Bs + (wc * 64 + n * 16 + l16) * 64 + q4 * 16);
#pragma unroll
        for (int m = 0; m < 4; m++)
#pragma unroll
            for (int n = 0; n < 4; n++)
                acc[m][n] = __builtin_amdgcn_mfma_f32_16x16x32_bf16(a[m], b[n], acc[m][n], 0, 0, 0);
    }
    const int rb = arow0 + wr * 64, cb = wrow0 + wc * 64;
#pragma unroll
    for (int m = 0; m < 4; m++)
#pragma unroll
        for (int n = 0; n < 4; n++)
#pragma unroll
            for (int r = 0; r < 4; r++) {
                const int row = rb + m * 16 + q4 * 4 + r;
                const int col = cb + n * 16 + l16;
                const float v = acc[m][n][r];
                if (MODE == 0) {
                    ((unsigned short*)Y)[(long)row * 1024 + col] = f2bf(v);
                } else if (MODE == 1) {
                    const int bb = row >> 12, s = row & 4095;
                    const int hh = col >> 6, dk = col & 63;
                    ((unsigned short*)Y)[(((long)(bb * Hh + hh) * DKk + dk) << 12) + s] = f2bf(v);
                } else if (MODE == 3) {
                    ((unsigned short*)Y)[(long)row * 1024 + col] = f2bf(v * 0.1803368801111244f);
                } else {
                    ((float*)Y)[(long)row * 1024 + col] = v;
                }
            }
}

// ---------------- flash attention: QB=256, 8 waves x 32 q-rows --------------
// grid (S/256, H, B), 512 threads = 8 waves; each wave owns 32 q-rows.
// Maxless exp2 softmax (Q pre-scaled by 0.125*log2e); li via pairwise adds +
// shfl_xor(32). PV: O^T = V^T P^T, P in-register (cvt_pk + permlane32_swap).
// R12 sync skeleton: [compute][barrier][stage kt+2 + vmcnt(2)][barrier].
// LDS (32KB): [0,8K) K0 | [8K,16K) V0 | [16K,24K) K1 | [24K,32K) V1;
// Q staging (32KB) strictly precedes K/V staging (vmcnt(0) fence).
__global__ __launch_bounds__(512, 4) void attn_fwd(const unsigned short* __restrict__ qp,
                                                   const unsigned short* __restrict__ kp,
                                                   const unsigned short* __restrict__ vt,
                                                   unsigned short* __restrict__ xo) {
    __shared__ __align__(16) char smem[32768];
    const int t = threadIdx.x;
    const int wid = t >> 6, lane = t & 63;
    const int l5 = lane & 31;
    const int ihi = lane >> 5;
    const int swz5 = (l5 & 7) ^ ((l5 >> 3) & 3);
    const int qt = blockIdx.x, h = blockIdx.y, b = blockIdx.z;
    const unsigned short* qbase = qp + ((long)b * Ss + qt * 256) * Dd + h * 64;
    const unsigned short* kbase = kp + (long)b * Ss * Dd + h * 64;
    const unsigned short* vbase = vt + (long)(b * Hh + h) * DKk * Ss;

    // staging geometry: 512 threads cover 8KB/call; row r0 in 0..63
    const int r0 = t >> 3;
    const int s0i = t & 7;
    const int cb0 = s0i ^ (r0 & 7) ^ ((r0 >> 3) & 3);  // logical col-block
    const int o0 = t * 16;                             // 0..8191
    const unsigned short* qsrc = qbase + (long)r0 * Dd + cb0 * 8;
    const unsigned short* ksrc = kbase + (long)r0 * Dd + cb0 * 8;
    const unsigned short* vsrc = vbase + (long)r0 * Ss + cb0 * 8;

    // ---- phase 1: Q (32KB, 4 calls) fully lands before K/V staging
#pragma unroll
    for (int i = 0; i < 4; i++)
        gload16(qsrc + (long)i * 64 * Dd, smem + i * 8192 + o0);
    asm volatile("s_waitcnt vmcnt(0)" ::: "memory");
    __builtin_amdgcn_s_barrier();
    asm volatile("" ::: "memory");

    // Q fragments: wave wid owns q-rows wid*32..wid*32+31 (chunk wid, 4KB)
    bf16x8 bQ[4];
#pragma unroll
    for (int m = 0; m < 4; m++) {
        const int slot = (m * 2 + ihi) ^ swz5;
        bQ[m] = *(const bf16x8*)(smem + wid * 4096 + l5 * 128 + (slot << 4));
    }
    asm volatile("s_waitcnt lgkmcnt(0)" ::: "memory");
    __builtin_amdgcn_s_barrier();                      // all waves done with Q
    asm volatile("" ::: "memory");

    // ---- phase 2: stage tiles 0 and 1 (K: 1 call, V: 1 call each)
    gload16(ksrc,                smem + o0);
    gload16(vsrc,                smem + 8192 + o0);
    gload16(ksrc + 64 * Dd,      smem + 16384 + o0);
    gload16(vsrc + 64,           smem + 24576 + o0);
    const unsigned short* pk = ksrc + 128 * Dd;
    const unsigned short* pv = vsrc + 128;
    asm volatile("s_waitcnt vmcnt(2)" ::: "memory");   // tile 0 landed
    __builtin_amdgcn_s_barrier();
    asm volatile("" ::: "memory");

    int adm[4];
#pragma unroll
    for (int m = 0; m < 4; m++)
        adm[m] = l5 * 128 + ((((m * 2 + ihi) ^ swz5)) << 4);

    f32x16 accO[2] = {};                     // [dblk]
    float li = 0.f;

    for (int kt2 = 0; kt2 < 64; kt2 += 2) {
#pragma unroll
        for (int hf = 0; hf < 2; hf++) {
            const int kt = kt2 + hf;
            const int BO = hf << 14;
            const char* Kc = smem + BO;
            const char* Vc = smem + BO + 8192;
            // ---- S^T = K Q^T : D[row=k][col=q=l5]
            f32x16 accS[2] = {};             // [kb]
            __builtin_amdgcn_s_setprio(1);
#pragma unroll
            for (int m = 0; m < 4; m++) {
                const bf16x8 aK0 = *(const bf16x8*)(Kc + adm[m]);
                const bf16x8 aK1 = *(const bf16x8*)(Kc + 4096 + adm[m]);
                accS[0] = MFMA16(aK0, bQ[m], accS[0]);
                accS[1] = MFMA16(aK1, bQ[m], accS[1]);
            }
            // ---- PV: per m-group, exp2/cvt/permlane then 2 MFMA
            float ps = 0.f;
#pragma unroll
            for (int m = 0; m < 4; m++) {
                const bf16x8 aV0 = *(const bf16x8*)(Vc + adm[m]);
                const bf16x8 aV1 = *(const bf16x8*)(Vc + 4096 + adm[m]);
                const int kb = m >> 1, sx = (m & 1) * 2;
                unsigned w00, w01, w10, w11;
                {
                    const float a0 = __builtin_amdgcn_exp2f(accS[kb][4 * sx + 0]);
                    const float a1 = __builtin_amdgcn_exp2f(accS[kb][4 * sx + 1]);
                    const float a2 = __builtin_amdgcn_exp2f(accS[kb][4 * sx + 2]);
                    const float a3 = __builtin_amdgcn_exp2f(accS[kb][4 * sx + 3]);
                    const float b0 = __builtin_amdgcn_exp2f(accS[kb][4 * sx + 4]);
                    const float b1 = __builtin_amdgcn_exp2f(accS[kb][4 * sx + 5]);
                    const float b2 = __builtin_amdgcn_exp2f(accS[kb][4 * sx + 6]);
                    const float b3 = __builtin_amdgcn_exp2f(accS[kb][4 * sx + 7]);
                    ps += ((a0 + a1) + (a2 + a3)) + ((b0 + b1) + (b2 + b3));
                    asm("v_cvt_pk_bf16_f32 %0, %1, %2" : "=v"(w00) : "v"(a0), "v"(a1));
                    asm("v_cvt_pk_bf16_f32 %0, %1, %2" : "=v"(w01) : "v"(a2), "v"(a3));
                    asm("v_cvt_pk_bf16_f32 %0, %1, %2" : "=v"(w10) : "v"(b0), "v"(b1));
                    asm("v_cvt_pk_bf16_f32 %0, %1, %2" : "=v"(w11) : "v"(b2), "v"(b3));
                }
                asm("v_permlane32_swap_b32 %0, %1" : "+v"(w00), "+v"(w10));
                asm("v_permlane32_swap_b32 %0, %1" : "+v"(w01), "+v"(w11));
                union { unsigned u[4]; bf16x8 v; } fr;
                fr.u[0] = w00; fr.u[1] = w01; fr.u[2] = w10; fr.u[3] = w11;
                accO[0] = MFMA16(aV0, fr.v, accO[0]);
                accO[1] = MFMA16(aV1, fr.v, accO[1]);
            }
            __builtin_amdgcn_s_setprio(0);
            li += ps + __shfl_xor(ps, 32, 64);
            // ---- counted-vmcnt barrier pair (R12 skeleton)
            __builtin_amdgcn_s_barrier();          // all waves done reading buf[hf]
            asm volatile("" ::: "memory");
            if (kt < 62) {
                char* dst = smem + BO;
                gload16(pk, dst + o0);
                gload16(pv, dst + 8192 + o0);
                pk += 64 * Dd;
                pv += 64;
                asm volatile("s_waitcnt vmcnt(2)" ::: "memory");  // tile kt+1 landed
            } else {
                asm volatile("s_waitcnt vmcnt(0)" ::: "memory");  // tail: drain
            }
            __builtin_amdgcn_s_barrier();          // buf[hf^1] readable by all
            asm volatile("" ::: "memory");
        }
    }

    // ---- epilogue: O^T -> LDS transpose (whole 32KB) -> coalesced store
    const float rli = 1.0f / li;
#pragma unroll
    for (int dblk = 0; dblk < 2; dblk++)
#pragma unroll
        for (int tt = 0; tt < 8; tt++) {
            const unsigned short b0 = f2bf(accO[dblk][2 * tt] * rli);
            const unsigned short b1 = f2bf(accO[dblk][2 * tt + 1] * rli);
            const int slot = (dblk * 4 + (tt >> 1)) ^ swz5;
            const int phys = wid * 4096 + l5 * 128 + (slot << 4) + ihi * 8 + (tt & 1) * 4;
            *(unsigned*)(smem + phys) = ((unsigned)b1 << 16) | b0;
        }
    __syncthreads();
#pragma unroll
    for (int p = 0; p < 4; p++) {
        const uint4 val = *(const uint4*)(smem + p * 8192 + o0);
        const long row = (long)qt * 256 + p * 64 + r0;
        *(uint4*)(xo + ((long)b * Ss + row) * Dd + h * 64 + cb0 * 8) = val;
    }
}

extern "C" void kernel_launch(void* const* d_in, const int* in_sizes, int n_in,
                              void* d_out, int out_size, void* d_ws, size_t ws_size,
                              hipStream_t stream) {
    const float* q  = (const float*)d_in[0];
    const float* k  = (const float*)d_in[1];
    const float* v  = (const float*)d_in[2];
    const float* wq = (const float*)d_in[3];
    const float* wk = (const float*)d_in[4];
    const float* wv = (const float*)d_in[5];
    const float* w0 = (const float*)d_in[6];

    unsigned short* ws = (unsigned short*)d_ws;
    const long NE = (long)Bb * Ss * Dd;        // 8388608
    unsigned short* qb  = ws;                  // q bf16, later kp
    unsigned short* kb  = ws + NE;             // k bf16, later vt
    unsigned short* vb  = ws + 2 * NE;         // v bf16, later xo
    unsigned short* x1  = ws + 3 * NE;         // qp (pre-scaled by 0.125*log2e)
    unsigned short* wqb = ws + 4 * NE;
    unsigned short* wkb = wqb + 1048576;
    unsigned short* wvb = wkb + 1048576;
    unsigned short* w0b = wvb + 1048576;

    cvt_all<<<2048, 256, 0, stream>>>(q, k, v, wq, wk, wv, w0, ws);

    dim3 gg(64, 8);
    gemm_bt<3><<<gg, 256, 0, stream>>>(qb, wqb, x1);    // qp * 0.125*log2e
    gemm_bt<0><<<gg, 256, 0, stream>>>(kb, wkb, qb);    // kp (q bf16 dead)
    gemm_bt<1><<<gg, 256, 0, stream>>>(vb, wvb, kb);    // vt (k bf16 dead)
    dim3 ga(16, 16, 2);
    attn_fwd<<<ga, 512, 0, stream>>>(x1, qb, kb, vb);   // xo (v bf16 dead)
    gemm_bt<2><<<gg, 256, 0, stream>>>(vb, w0b, (float*)d_out);
}